// Round 16
// baseline (571.089 us; speedup 1.0000x reference)
//
#include <hip/hip_runtime.h>
#include <hip/hip_bf16.h>
#include <math.h>

#define B_    8
#define C_    256
#define N_    16384
#define H_    4
#define D_    32
#define HID_  128
#define ROWS_ 384
#define SCALE 0.17677669529663687f   // 32^-0.5

typedef __attribute__((ext_vector_type(8))) short bf16x8;
typedef __attribute__((ext_vector_type(16))) float f32x16;
typedef __attribute__((ext_vector_type(4))) unsigned int u32x4;

__device__ __forceinline__ short f2bf(float f) {
    union { __hip_bfloat16 h; short s; } u;
    u.h = __float2bfloat16(f);
    return u.s;
}
__device__ __forceinline__ float bf2f(short s) {
    union { unsigned u; float f; } x;
    x.u = ((unsigned)(unsigned short)s) << 16;
    return x.f;
}

// ------------------------------------------------------------------
// Kernel 0: build fragment-major bf16 qkv weights + bf16 w_out
// ------------------------------------------------------------------
__global__ __launch_bounds__(256) void k_conv(
    const float* __restrict__ wqkv, const float* __restrict__ wout,
    short* __restrict__ wrearr, short* __restrict__ woutb)
{
    int i = blockIdx.x * 256 + threadIdx.x;
    if (i < 12288) {
        int tile = i >> 10;
        int ks   = (i >> 6) & 15;
        int l    = i & 63;
        int row  = tile * 32 + (l & 31);
        int k0   = ks * 16 + (l >> 5) * 8;
        const float* src = wqkv + row * 256 + k0;
        float4 f0 = *(const float4*)(src);
        float4 f1 = *(const float4*)(src + 4);
        short o[8] = {f2bf(f0.x), f2bf(f0.y), f2bf(f0.z), f2bf(f0.w),
                      f2bf(f1.x), f2bf(f1.y), f2bf(f1.z), f2bf(f1.w)};
        *(uint4*)(wrearr + (size_t)i * 8) = *(uint4*)o;
    } else {
        int j = (i - 12288) * 4;
        float4 f = *(const float4*)(wout + j);
        short4 s; s.x = f2bf(f.x); s.y = f2bf(f.y); s.z = f2bf(f.z); s.w = f2bf(f.w);
        *(short4*)(woutb + j) = s;
    }
}

// ------------------------------------------------------------------
// Kernel 0.5: streaming transpose+convert, full-128B-line image
// writes, NONTEMPORAL (via ext_vector_type — HIP uint4 is rejected
// by __builtin_nontemporal_store). Block = (b, cg=64 c-rows, nw=512 n).
// ------------------------------------------------------------------
__global__ __launch_bounds__(512, 2) void k_xT(
    const float* __restrict__ x, short* __restrict__ ximg)
{
    __shared__ short xs[512 * 66];           // [n][c] pitch 66 -> 67.6 KB
    const int blk = blockIdx.x;
    const int cg  = blk & 3;
    const int nw  = (blk >> 2) & 31;
    const int b   = blk >> 7;
    const int t   = threadIdx.x;

    // ---- phase A: read [64c][512n] fp32 coalesced, convert, LDS [n][c] ----
    {
        const int c_l = t >> 3;              // 0..63 (local c row)
        const int lj  = t & 7;
        const float* xr = x + ((size_t)b * C_ + cg * 64 + c_l) * N_ + nw * 512;
#pragma unroll
        for (int i = 0; i < 16; i++) {
            int n0 = i * 32 + lj * 4;
            float4 v = *(const float4*)(xr + n0);
            xs[(n0 + 0) * 66 + c_l] = f2bf(v.x);
            xs[(n0 + 1) * 66 + c_l] = f2bf(v.y);
            xs[(n0 + 2) * 66 + c_l] = f2bf(v.z);
            xs[(n0 + 3) * 66 + c_l] = f2bf(v.w);
        }
    }
    __syncthreads();

    // ---- phase B: per n, one full 128B line (granule-permuted), NT ----
    {
        const int j = t & 7;
        short* chunkb = ximg + (size_t)b * 128 * 32768;
#pragma unroll
        for (int p = 0; p < 8; p++) {
            int n_l = p * 64 + (t >> 3);     // 0..511
            int n_g = nw * 512 + n_l;
            u32x4 v = *(const u32x4*)(&xs[n_l * 66 + j * 8]);
            int line = cg ^ ((n_g >> 3) & 3);
            int gran = j ^ (n_g & 7);
            size_t ad = (size_t)(n_g >> 7) * 32768
                      + (size_t)(n_g & 127) * 256
                      + line * 64 + gran * 8;
            __builtin_nontemporal_store(v, (u32x4*)(chunkb + ad));
        }
    }
}

// ------------------------------------------------------------------
// Kernel 1: stage = PLAIN linear 64 KB chunk copy (uint4 loads ->
// LDS). No global_load_lds (pathological on freshly-written lines).
// GEMM/softmax/ekv/ctx identical to round 13/14 (verified correct).
// ------------------------------------------------------------------
__global__ __launch_bounds__(512, 4) void k_qkv(
    const short* __restrict__ ximg, const short* __restrict__ wrearr,
    short* __restrict__ qtb, short* __restrict__ part16,
    float* __restrict__ partden)
{
    __shared__ __align__(16) char img[65536];   // bf16 [128n][256k] swz16B;
                                                // becomes ek/v tiles after MFMA

    const int orig = blockIdx.x;
    const int swz  = (orig & 7) * 128 + (orig >> 3);   // bijective, 1024 = 8*128
    const int b    = swz >> 7;
    const int nwin = swz & 127;
    const int nb   = nwin << 7;
    const int t    = threadIdx.x;
    const int l    = t & 63;
    const int wv   = t >> 6;             // 0..7
    const int h    = wv & 3;
    const int ch   = wv >> 2;
    const int c31  = l & 31;
    const int hf   = l >> 5;

    // ---- stage: plain linear 64 KB copy (chunk was written by k_xT) ----
    {
        const uint4* src = (const uint4*)(ximg + (size_t)swz * 32768);
        uint4* dst = (uint4*)img;
#pragma unroll
        for (int i = 0; i < 8; i++)
            dst[i * 512 + t] = src[i * 512 + t];
    }
    __syncthreads();

    // ---- MFMA K-loop: 16 k-steps of 16; A-frags coalesced + prefetched ----
    f32x16 acc[3][2];
#pragma unroll
    for (int ti = 0; ti < 3; ti++)
#pragma unroll
        for (int ct = 0; ct < 2; ct++)
#pragma unroll
            for (int r = 0; r < 16; r++) acc[ti][ct][r] = 0.f;

    const bf16x8* wp = (const bf16x8*)wrearr + (size_t)h * 1024 + l;
    bf16x8 afN0 = wp[0], afN1 = wp[4096], afN2 = wp[8192];
    const char* smB0 = img + (ch * 64 + c31) * 512;
    const char* smB1 = img + (ch * 64 + 32 + c31) * 512;
#pragma unroll
    for (int ks = 0; ks < 16; ks++) {
        bf16x8 af0 = afN0, af1 = afN1, af2 = afN2;
        if (ks < 15) {
            afN0 = wp[(ks + 1) * 64];
            afN1 = wp[4096 + (ks + 1) * 64];
            afN2 = wp[8192 + (ks + 1) * 64];
        }
        const int slot = 2 * ks + hf;
        bf16x8 bfr0 = *(const bf16x8*)(smB0 + 16 * (slot ^ c31));
        bf16x8 bfr1 = *(const bf16x8*)(smB1 + 16 * (slot ^ c31));
        acc[0][0] = __builtin_amdgcn_mfma_f32_32x32x16_bf16(af0, bfr0, acc[0][0], 0, 0, 0);
        acc[0][1] = __builtin_amdgcn_mfma_f32_32x32x16_bf16(af0, bfr1, acc[0][1], 0, 0, 0);
        acc[1][0] = __builtin_amdgcn_mfma_f32_32x32x16_bf16(af1, bfr0, acc[1][0], 0, 0, 0);
        acc[1][1] = __builtin_amdgcn_mfma_f32_32x32x16_bf16(af1, bfr1, acc[1][1], 0, 0, 0);
        acc[2][0] = __builtin_amdgcn_mfma_f32_32x32x16_bf16(af2, bfr0, acc[2][0], 0, 0, 0);
        acc[2][1] = __builtin_amdgcn_mfma_f32_32x32x16_bf16(af2, bfr1, acc[2][1], 0, 0, 0);
    }

    // C layout: col = lane&31, row = (r&3)+8*(r>>2)+4*hf

    // ---- q softmax -> direct coalesced global store, [b][hid][n] layout ----
#pragma unroll
    for (int ct = 0; ct < 2; ct++) {
        float mx = -1e30f;
#pragma unroll
        for (int r = 0; r < 16; r++) mx = fmaxf(mx, acc[0][ct][r]);
        mx = fmaxf(mx, __shfl_xor(mx, 32));
        float e[16]; float s = 0.f;
#pragma unroll
        for (int r = 0; r < 16; r++) { e[r] = __expf(acc[0][ct][r] - mx); s += e[r]; }
        s += __shfl_xor(s, 32);
        float inv = SCALE / s;
        short* qp = qtb + ((size_t)b * HID_ + h * 32) * N_ + nb + ch * 64 + ct * 32 + c31;
#pragma unroll
        for (int r = 0; r < 16; r++) {
            int rm = (r & 3) + 8 * (r >> 2) + 4 * hf;
            qp[(size_t)rm * N_] = f2bf(e[r] * inv);
        }
    }
    __syncthreads();   // all MFMA reads of img complete across all 8 waves

    // ---- ek/v -> per-wave swizzled bf16 tiles (overwrite img; own region) ----
    char* ekb = img + wv * 8192;
    char* vvb = ekb + 4096;
#pragma unroll
    for (int ct = 0; ct < 2; ct++)
#pragma unroll
        for (int r = 0; r < 16; r++) {
            int rm = (r & 3) + 8 * (r >> 2) + 4 * hf;
            int n  = ct * 32 + c31;
            int ad = rm * 128 + ((2 * n) ^ ((rm & 7) << 4));
            *(short*)(ekb + ad) = f2bf(__expf(acc[1][ct][r]));
            *(short*)(vvb + ad) = f2bf(acc[2][ct][r]);
        }
    // no barrier: each wave reads only its own ekb/vvb

    // ---- ctx MFMA: ctx[d][e] = sum_n ek[d,n] v[e,n] (this wave's 64 n) ----
    f32x16 cD, dD;
#pragma unroll
    for (int r = 0; r < 16; r++) { cD[r] = 0.f; dD[r] = 0.f; }
    bf16x8 ones;
#pragma unroll
    for (int i = 0; i < 8; i++) ones[i] = (short)0x3F80;   // bf16 1.0
#pragma unroll
    for (int ks = 0; ks < 4; ks++) {
        int slot = 2 * ks + hf;
        bf16x8 ea = *(const bf16x8*)(ekb + c31 * 128 + 16 * (slot ^ (c31 & 7)));
        bf16x8 vb = *(const bf16x8*)(vvb + c31 * 128 + 16 * (slot ^ (c31 & 7)));
        cD = __builtin_amdgcn_mfma_f32_32x32x16_bf16(ea, vb,   cD, 0, 0, 0);
        dD = __builtin_amdgcn_mfma_f32_32x32x16_bf16(ea, ones, dD, 0, 0, 0);
    }

    // ---- store per-block ctx partials (layout matches k_red) ----
    const int q64 = nwin * 2 + ch;
    short* pb = part16 + ((size_t)(b * 256 + q64) * 4 + h) * 1024;
#pragma unroll
    for (int r = 0; r < 16; r++) {
        int rm = (r & 3) + 8 * (r >> 2) + 4 * hf;
        pb[rm * 32 + c31] = f2bf(cD[r]);
    }
    if (c31 == 0) {
        float* pd = partden + ((size_t)(b * 256 + q64) * 4 + h) * 32;
#pragma unroll
        for (int r = 0; r < 16; r++) {
            int rm = (r & 3) + 8 * (r >> 2) + 4 * hf;
            pd[rm] = dD[r];
        }
    }
}

// ------------------------------------------------------------------
// Kernel 1.5: reduce 256 partials per (b,h)  (unchanged)
// ------------------------------------------------------------------
__global__ __launch_bounds__(256) void k_red(
    const short* __restrict__ part16, const float* __restrict__ partden,
    short* __restrict__ ctxbf)
{
    __shared__ float den_s[32];
    const int bh = blockIdx.x;
    const int b  = bh >> 2, h = bh & 3;
    const int t  = threadIdx.x;
    const int d  = t >> 3;
    const int e4 = (t & 7) * 4;

    const short* p0 = part16 + ((size_t)(b * 256) * 4 + h) * 1024 + d * 32 + e4;
    float s0 = 0.f, s1 = 0.f, s2 = 0.f, s3 = 0.f;
    for (int q = 0; q < 256; q++) {
        short4 v = *(const short4*)(p0 + (size_t)q * 4096);
        s0 += bf2f(v.x); s1 += bf2f(v.y); s2 += bf2f(v.z); s3 += bf2f(v.w);
    }
    if ((t & 7) == 0) {
        const float* pd = partden + ((size_t)(b * 256) * 4 + h) * 32 + d;
        float ds = 0.f;
        for (int q = 0; q < 256; q++) ds += pd[(size_t)q * 128];
        den_s[d] = ds;
    }
    __syncthreads();
    float inv = 1.0f / den_s[d];
    short* cb = ctxbf + (size_t)bh * 1024 + d;
    cb[(e4 + 0) * 32] = f2bf(s0 * inv);
    cb[(e4 + 1) * 32] = f2bf(s1 * inv);
    cb[(e4 + 2) * 32] = f2bf(s2 * inv);
    cb[(e4 + 3) * 32] = f2bf(s3 * inv);
}

// ------------------------------------------------------------------
// Kernel 2: hidden + w_out GEMM + RMS (unchanged; nt stores kept)
// ------------------------------------------------------------------
__global__ __launch_bounds__(256, 3) void k_out(
    const short* __restrict__ qtb, const short* __restrict__ ctxbf,
    const short* __restrict__ woutb, const float* __restrict__ bout,
    const float* __restrict__ g, float* __restrict__ out)
{
    __shared__ __align__(16) char  hidS[16384];
    __shared__ float gl[C_], bl[C_];
    __shared__ float red[4][64];
    __shared__ float nrm[64];

    const int blk = blockIdx.x;
    const int b   = blk >> 8;
    const int n0  = (blk & 255) << 6;
    const int t   = threadIdx.x;
    const int l   = t & 63;
    const int wv  = t >> 6;
    const int c31 = l & 31;
    const int hf  = l >> 5;

    gl[t] = g[t];
    bl[t] = bout[t];
    __syncthreads();

    f32x16 hD[2];
#pragma unroll
    for (int ct = 0; ct < 2; ct++)
#pragma unroll
        for (int r = 0; r < 16; r++) hD[ct][r] = 0.f;
    const short* qb = qtb + (size_t)b * HID_ * N_ + n0;
    const short* cb = ctxbf + ((size_t)(b * H_ + wv) * 32 + c31) * 32;
#pragma unroll
    for (int ks = 0; ks < 2; ks++) {
        int k0 = ks * 16 + hf * 8;
        bf16x8 af = *(const bf16x8*)(cb + k0);
#pragma unroll
        for (int ct = 0; ct < 2; ct++) {
            bf16x8 bq;
#pragma unroll
            for (int i = 0; i < 8; i++)
                bq[i] = qb[(size_t)(wv * 32 + k0 + i) * N_ + ct * 32 + c31];
            hD[ct] = __builtin_amdgcn_mfma_f32_32x32x16_bf16(af, bq, hD[ct], 0, 0, 0);
        }
    }
#pragma unroll
    for (int ct = 0; ct < 2; ct++)
#pragma unroll
        for (int r = 0; r < 16; r++) {
            int rm = (r & 3) + 8 * (r >> 2) + 4 * hf;
            int hfull = wv * 32 + rm;
            int n = ct * 32 + c31;
            int ad = n * 256 + ((2 * hfull) ^ ((n & 15) << 4));
            *(short*)(hidS + ad) = f2bf(hD[ct][r]);
        }
    __syncthreads();

    f32x16 yacc[2][2];
#pragma unroll
    for (int rt = 0; rt < 2; rt++)
#pragma unroll
        for (int ct = 0; ct < 2; ct++)
#pragma unroll
            for (int r = 0; r < 16; r++) yacc[rt][ct][r] = 0.f;

#pragma unroll
    for (int ks = 0; ks < 8; ks++) {
        int k0 = ks * 16 + hf * 8;
        int sx = 2 * ks + hf;
        bf16x8 bq0 = *(const bf16x8*)(hidS + (c31)      * 256 + 16 * (sx ^ (c31 & 15)));
        bf16x8 bq1 = *(const bf16x8*)(hidS + (c31 + 32) * 256 + 16 * (sx ^ (c31 & 15)));
#pragma unroll
        for (int rt = 0; rt < 2; rt++) {
            bf16x8 af = *(const bf16x8*)(woutb + (wv * 64 + rt * 32 + c31) * HID_ + k0);
            yacc[rt][0] = __builtin_amdgcn_mfma_f32_32x32x16_bf16(af, bq0, yacc[rt][0], 0, 0, 0);
            yacc[rt][1] = __builtin_amdgcn_mfma_f32_32x32x16_bf16(af, bq1, yacc[rt][1], 0, 0, 0);
        }
    }

#pragma unroll
    for (int rt = 0; rt < 2; rt++)
#pragma unroll
        for (int r = 0; r < 16; r++) {
            int rm = (r & 3) + 8 * (r >> 2) + 4 * hf;
            float bo = bl[wv * 64 + rt * 32 + rm];
            yacc[rt][0][r] += bo;
            yacc[rt][1][r] += bo;
        }
#pragma unroll
    for (int ct = 0; ct < 2; ct++) {
        float s = 0.f;
#pragma unroll
        for (int rt = 0; rt < 2; rt++)
#pragma unroll
            for (int r = 0; r < 16; r++) s = fmaf(yacc[rt][ct][r], yacc[rt][ct][r], s);
        s += __shfl_xor(s, 32);
        if (hf == 0) red[wv][ct * 32 + c31] = s;
    }
    __syncthreads();
    if (t < 64) {
        float S = red[0][t] + red[1][t] + red[2][t] + red[3][t];
        nrm[t] = 16.0f / fmaxf(sqrtf(S), 1e-12f);
    }
    __syncthreads();

    float* ob = out + (size_t)b * C_ * N_ + n0;
#pragma unroll
    for (int rt = 0; rt < 2; rt++)
#pragma unroll
        for (int r = 0; r < 16; r++) {
            int rm = (r & 3) + 8 * (r >> 2) + 4 * hf;
            int c  = wv * 64 + rt * 32 + rm;
            float gc = gl[c];
#pragma unroll
            for (int ct = 0; ct < 2; ct++) {
                int n = ct * 32 + c31;
                __builtin_nontemporal_store(yacc[rt][ct][r] * gc * nrm[n],
                                            &ob[(size_t)c * N_ + n]);
            }
        }
}

// ------------------------------------------------------------------
extern "C" void kernel_launch(void* const* d_in, const int* in_sizes, int n_in,
                              void* d_out, int out_size, void* d_ws, size_t ws_size,
                              hipStream_t stream)
{
    const float* x    = (const float*)d_in[0];
    const float* wqkv = (const float*)d_in[1];
    const float* wout = (const float*)d_in[2];
    const float* bout = (const float*)d_in[3];
    const float* g    = (const float*)d_in[4];
    float* out = (float*)d_out;

    // ximg (67 MB, swizzled per-chunk image) lives in the FIRST HALF of
    // d_out: k_xT writes it (NT), k_qkv consumes it, k_out rewrites d_out.
    short* ximg    = (short*)d_out;

    short* qtb     = (short*)d_ws;
    short* part16  = qtb + (size_t)B_ * N_ * HID_;
    float* partden = (float*)(part16 + (size_t)2048 * 4 * 1024);
    short* ctxbf   = (short*)(partden + (size_t)2048 * 4 * 32);
    short* wrearr  = ctxbf + (size_t)B_ * H_ * 32 * 32;
    short* woutb   = wrearr + (size_t)12288 * 8;

    k_conv<<<80, 256, 0, stream>>>(wqkv, wout, wrearr, woutb);
    k_xT<<<1024, 512, 0, stream>>>(x, ximg);
    k_qkv<<<1024, 512, 0, stream>>>(ximg, wrearr, qtb, part16, partden);
    k_red<<<B_ * H_, 256, 0, stream>>>(part16, partden, ctxbf);
    k_out<<<B_ * (N_ / 64), 256, 0, stream>>>(qtb, ctxbf, woutb, bout, g, out);
}

// Round 17
// 125.724 us; speedup vs baseline: 4.5424x; 4.5424x over previous
//
#include <hip/hip_runtime.h>
#include <hip/hip_bf16.h>
#include <math.h>

#define B_    8
#define C_    256
#define N_    16384
#define H_    4
#define D_    32
#define HID_  128
#define ROWS_ 384
#define SCALE 0.17677669529663687f   // 32^-0.5

typedef __attribute__((ext_vector_type(8))) short bf16x8;
typedef __attribute__((ext_vector_type(16))) float f32x16;

__device__ __forceinline__ short f2bf(float f) {
    union { __hip_bfloat16 h; short s; } u;
    u.h = __float2bfloat16(f);
    return u.s;
}
__device__ __forceinline__ float bf2f(short s) {
    union { unsigned u; float f; } x;
    x.u = ((unsigned)(unsigned short)s) << 16;
    return x.f;
}

// ------------------------------------------------------------------
// Kernel 0: build fragment-major bf16 qkv weights + bf16 w_out
// ------------------------------------------------------------------
__global__ __launch_bounds__(256) void k_conv(
    const float* __restrict__ wqkv, const float* __restrict__ wout,
    short* __restrict__ wrearr, short* __restrict__ woutb)
{
    int i = blockIdx.x * 256 + threadIdx.x;
    if (i < 12288) {
        int tile = i >> 10;
        int ks   = (i >> 6) & 15;
        int l    = i & 63;
        int row  = tile * 32 + (l & 31);
        int k0   = ks * 16 + (l >> 5) * 8;
        const float* src = wqkv + row * 256 + k0;
        float4 f0 = *(const float4*)(src);
        float4 f1 = *(const float4*)(src + 4);
        short o[8] = {f2bf(f0.x), f2bf(f0.y), f2bf(f0.z), f2bf(f0.w),
                      f2bf(f1.x), f2bf(f1.y), f2bf(f1.z), f2bf(f1.w)};
        *(uint4*)(wrearr + (size_t)i * 8) = *(uint4*)o;
    } else {
        int j = (i - 12288) * 4;
        float4 f = *(const float4*)(wout + j);
        short4 s; s.x = f2bf(f.x); s.y = f2bf(f.y); s.z = f2bf(f.z); s.w = f2bf(f.w);
        *(short4*)(woutb + j) = s;
    }
}

// ------------------------------------------------------------------
// Kernel 1: EXACT round-9 k_qkv (fastest measured: ~100 us, occ 41%).
// BN=128, 8 waves/512 thr, plain strided fp32 stage -> swizzled bf16
// LDS image (64 KB -> 2 blocks/CU), fragment-major A, reg prefetch,
// no-atomic partials.
// ------------------------------------------------------------------
__global__ __launch_bounds__(512, 4) void k_qkv(
    const float* __restrict__ x, const short* __restrict__ wrearr,
    short* __restrict__ qtb, short* __restrict__ part16,
    float* __restrict__ partden)
{
    __shared__ __align__(16) char smA[65536];

    const int orig = blockIdx.x;
    const int swz  = (orig & 7) * 128 + (orig >> 3);   // bijective, 1024 = 8*128
    const int b    = swz >> 7;
    const int nwin = swz & 127;
    const int nb   = nwin << 7;          // 128-col window base
    const int t    = threadIdx.x;
    const int l    = t & 63;
    const int wv   = t >> 6;             // 0..7
    const int h    = wv & 3;
    const int ch   = wv >> 2;            // 0/1 column half
    const int c31  = l & 31;
    const int hf   = l >> 5;

    // ---- stage x tile [256 k][128 n] -> bf16 transposed swizzled [n][k] ----
    {
        const int kg = t >> 5;           // 0..15
        const int n4 = (t & 31) * 4;     // 0..124
        const float* xb = x + (size_t)b * C_ * N_ + nb + n4;
#pragma unroll
        for (int it = 0; it < 4; it++) {
            const int k = it * 64 + kg * 4;
            const float* xp = xb + (size_t)k * N_;
            float4 r0 = *(const float4*)(xp);
            float4 r1 = *(const float4*)(xp + N_);
            float4 r2 = *(const float4*)(xp + 2 * (size_t)N_);
            float4 r3 = *(const float4*)(xp + 3 * (size_t)N_);
#define WRT(J, FLD) { short4 sv; sv.x = f2bf(r0.FLD); sv.y = f2bf(r1.FLD); \
    sv.z = f2bf(r2.FLD); sv.w = f2bf(r3.FLD); \
    int n_ = n4 + J; int ad_ = n_ * 512 + ((2 * k) ^ ((n_ & 31) << 4)); \
    *(short4*)(smA + ad_) = sv; }
            WRT(0, x) WRT(1, y) WRT(2, z) WRT(3, w)
#undef WRT
        }
    }
    __syncthreads();

    // ---- MFMA K-loop: 16 k-steps of 16; A-frags coalesced + prefetched ----
    f32x16 acc[3][2];
#pragma unroll
    for (int ti = 0; ti < 3; ti++)
#pragma unroll
        for (int ct = 0; ct < 2; ct++)
#pragma unroll
            for (int r = 0; r < 16; r++) acc[ti][ct][r] = 0.f;

    const bf16x8* wp = (const bf16x8*)wrearr + (size_t)h * 1024 + l;
    bf16x8 afN0 = wp[0], afN1 = wp[4096], afN2 = wp[8192];
    const char* smB0 = smA + (ch * 64 + c31) * 512;
    const char* smB1 = smA + (ch * 64 + 32 + c31) * 512;
#pragma unroll
    for (int ks = 0; ks < 16; ks++) {
        bf16x8 af0 = afN0, af1 = afN1, af2 = afN2;
        if (ks < 15) {
            afN0 = wp[(ks + 1) * 64];
            afN1 = wp[4096 + (ks + 1) * 64];
            afN2 = wp[8192 + (ks + 1) * 64];
        }
        const int slot = 2 * ks + hf;
        bf16x8 bfr0 = *(const bf16x8*)(smB0 + 16 * (slot ^ c31));
        bf16x8 bfr1 = *(const bf16x8*)(smB1 + 16 * (slot ^ c31));
        acc[0][0] = __builtin_amdgcn_mfma_f32_32x32x16_bf16(af0, bfr0, acc[0][0], 0, 0, 0);
        acc[0][1] = __builtin_amdgcn_mfma_f32_32x32x16_bf16(af0, bfr1, acc[0][1], 0, 0, 0);
        acc[1][0] = __builtin_amdgcn_mfma_f32_32x32x16_bf16(af1, bfr0, acc[1][0], 0, 0, 0);
        acc[1][1] = __builtin_amdgcn_mfma_f32_32x32x16_bf16(af1, bfr1, acc[1][1], 0, 0, 0);
        acc[2][0] = __builtin_amdgcn_mfma_f32_32x32x16_bf16(af2, bfr0, acc[2][0], 0, 0, 0);
        acc[2][1] = __builtin_amdgcn_mfma_f32_32x32x16_bf16(af2, bfr1, acc[2][1], 0, 0, 0);
    }

    // C layout: col = lane&31, row = (r&3)+8*(r>>2)+4*hf

    // ---- q softmax -> direct coalesced global store, [b][hid][n] layout ----
#pragma unroll
    for (int ct = 0; ct < 2; ct++) {
        float mx = -1e30f;
#pragma unroll
        for (int r = 0; r < 16; r++) mx = fmaxf(mx, acc[0][ct][r]);
        mx = fmaxf(mx, __shfl_xor(mx, 32));
        float e[16]; float s = 0.f;
#pragma unroll
        for (int r = 0; r < 16; r++) { e[r] = __expf(acc[0][ct][r] - mx); s += e[r]; }
        s += __shfl_xor(s, 32);
        float inv = SCALE / s;
        short* qp = qtb + ((size_t)b * HID_ + h * 32) * N_ + nb + ch * 64 + ct * 32 + c31;
#pragma unroll
        for (int r = 0; r < 16; r++) {
            int rm = (r & 3) + 8 * (r >> 2) + 4 * hf;
            qp[(size_t)rm * N_] = f2bf(e[r] * inv);
        }
    }
    __syncthreads();   // all MFMA reads of smA complete across all 8 waves

    // ---- ek/v -> per-wave swizzled bf16 tiles (overwrite smA; own region) ----
    char* ekb = smA + wv * 8192;
    char* vvb = ekb + 4096;
#pragma unroll
    for (int ct = 0; ct < 2; ct++)
#pragma unroll
        for (int r = 0; r < 16; r++) {
            int rm = (r & 3) + 8 * (r >> 2) + 4 * hf;
            int n  = ct * 32 + c31;
            int ad = rm * 128 + ((2 * n) ^ ((rm & 7) << 4));
            *(short*)(ekb + ad) = f2bf(__expf(acc[1][ct][r]));
            *(short*)(vvb + ad) = f2bf(acc[2][ct][r]);
        }
    // no barrier: each wave reads only its own ekb/vvb

    // ---- ctx MFMA: ctx[d][e] = sum_n ek[d,n] v[e,n] (this wave's 64 n) ----
    f32x16 cD, dD;
#pragma unroll
    for (int r = 0; r < 16; r++) { cD[r] = 0.f; dD[r] = 0.f; }
    bf16x8 ones;
#pragma unroll
    for (int i = 0; i < 8; i++) ones[i] = (short)0x3F80;   // bf16 1.0
#pragma unroll
    for (int ks = 0; ks < 4; ks++) {
        int slot = 2 * ks + hf;
        bf16x8 ea = *(const bf16x8*)(ekb + c31 * 128 + 16 * (slot ^ (c31 & 7)));
        bf16x8 vb = *(const bf16x8*)(vvb + c31 * 128 + 16 * (slot ^ (c31 & 7)));
        cD = __builtin_amdgcn_mfma_f32_32x32x16_bf16(ea, vb,   cD, 0, 0, 0);
        dD = __builtin_amdgcn_mfma_f32_32x32x16_bf16(ea, ones, dD, 0, 0, 0);
    }

    // ---- store per-block ctx partials (layout matches k_red) ----
    const int q64 = nwin * 2 + ch;       // 64-col tile index within batch, 0..255
    short* pb = part16 + ((size_t)(b * 256 + q64) * 4 + h) * 1024;
#pragma unroll
    for (int r = 0; r < 16; r++) {
        int rm = (r & 3) + 8 * (r >> 2) + 4 * hf;
        pb[rm * 32 + c31] = f2bf(cD[r]);
    }
    if (c31 == 0) {
        float* pd = partden + ((size_t)(b * 256 + q64) * 4 + h) * 32;
#pragma unroll
        for (int r = 0; r < 16; r++) {
            int rm = (r & 3) + 8 * (r >> 2) + 4 * hf;
            pd[rm] = dD[r];
        }
    }
}

// ------------------------------------------------------------------
// Kernel 1.5: reduce 256 partials per (b,h)  (unchanged)
// ------------------------------------------------------------------
__global__ __launch_bounds__(256) void k_red(
    const short* __restrict__ part16, const float* __restrict__ partden,
    short* __restrict__ ctxbf)
{
    __shared__ float den_s[32];
    const int bh = blockIdx.x;            // 32 = b*4 + h
    const int b  = bh >> 2, h = bh & 3;
    const int t  = threadIdx.x;
    const int d  = t >> 3;
    const int e4 = (t & 7) * 4;

    const short* p0 = part16 + ((size_t)(b * 256) * 4 + h) * 1024 + d * 32 + e4;
    float s0 = 0.f, s1 = 0.f, s2 = 0.f, s3 = 0.f;
    for (int q = 0; q < 256; q++) {
        short4 v = *(const short4*)(p0 + (size_t)q * 4096);
        s0 += bf2f(v.x); s1 += bf2f(v.y); s2 += bf2f(v.z); s3 += bf2f(v.w);
    }
    if ((t & 7) == 0) {
        const float* pd = partden + ((size_t)(b * 256) * 4 + h) * 32 + d;
        float ds = 0.f;
        for (int q = 0; q < 256; q++) ds += pd[(size_t)q * 128];
        den_s[d] = ds;
    }
    __syncthreads();
    float inv = 1.0f / den_s[d];
    short* cb = ctxbf + (size_t)bh * 1024 + d;     // [e][d] layout
    cb[(e4 + 0) * 32] = f2bf(s0 * inv);
    cb[(e4 + 1) * 32] = f2bf(s1 * inv);
    cb[(e4 + 2) * 32] = f2bf(s2 * inv);
    cb[(e4 + 3) * 32] = f2bf(s3 * inv);
}

// ------------------------------------------------------------------
// Kernel 2: hidden + w_out GEMM + RMS; NONTEMPORAL out stores
// (the r11 k_out — its total beat r9's despite a slower k_qkv).
// ------------------------------------------------------------------
__global__ __launch_bounds__(256, 3) void k_out(
    const short* __restrict__ qtb, const short* __restrict__ ctxbf,
    const short* __restrict__ woutb, const float* __restrict__ bout,
    const float* __restrict__ g, float* __restrict__ out)
{
    __shared__ __align__(16) char  hidS[16384];        // [n][128] bf16 swz16B
    __shared__ float gl[C_], bl[C_];
    __shared__ float red[4][64];
    __shared__ float nrm[64];

    const int blk = blockIdx.x;
    const int b   = blk >> 8;
    const int n0  = (blk & 255) << 6;
    const int t   = threadIdx.x;
    const int l   = t & 63;
    const int wv  = t >> 6;
    const int c31 = l & 31;
    const int hf  = l >> 5;

    gl[t] = g[t];
    bl[t] = bout[t];
    __syncthreads();

    // ---- hidden MFMA: wave wv -> head wv; hid[e][n] = sum_d ctxT[e][d] q~[d][n]
    f32x16 hD[2];
#pragma unroll
    for (int ct = 0; ct < 2; ct++)
#pragma unroll
        for (int r = 0; r < 16; r++) hD[ct][r] = 0.f;
    const short* qb = qtb + (size_t)b * HID_ * N_ + n0;
    const short* cb = ctxbf + ((size_t)(b * H_ + wv) * 32 + c31) * 32;
#pragma unroll
    for (int ks = 0; ks < 2; ks++) {
        int k0 = ks * 16 + hf * 8;
        bf16x8 af = *(const bf16x8*)(cb + k0);
#pragma unroll
        for (int ct = 0; ct < 2; ct++) {
            bf16x8 bq;
#pragma unroll
            for (int i = 0; i < 8; i++)
                bq[i] = qb[(size_t)(wv * 32 + k0 + i) * N_ + ct * 32 + c31];
            hD[ct] = __builtin_amdgcn_mfma_f32_32x32x16_bf16(af, bq, hD[ct], 0, 0, 0);
        }
    }
    // write hidden -> swizzled LDS [n][hfull]
#pragma unroll
    for (int ct = 0; ct < 2; ct++)
#pragma unroll
        for (int r = 0; r < 16; r++) {
            int rm = (r & 3) + 8 * (r >> 2) + 4 * hf;
            int hfull = wv * 32 + rm;
            int n = ct * 32 + c31;
            int ad = n * 256 + ((2 * hfull) ^ ((n & 15) << 4));
            *(short*)(hidS + ad) = f2bf(hD[ct][r]);
        }
    __syncthreads();

    // ---- w_out GEMM: wave wv -> c rows wv*64..+64 ----
    f32x16 yacc[2][2];
#pragma unroll
    for (int rt = 0; rt < 2; rt++)
#pragma unroll
        for (int ct = 0; ct < 2; ct++)
#pragma unroll
            for (int r = 0; r < 16; r++) yacc[rt][ct][r] = 0.f;

#pragma unroll
    for (int ks = 0; ks < 8; ks++) {
        int k0 = ks * 16 + hf * 8;
        int sx = 2 * ks + hf;
        bf16x8 bq0 = *(const bf16x8*)(hidS + (c31)      * 256 + 16 * (sx ^ (c31 & 15)));
        bf16x8 bq1 = *(const bf16x8*)(hidS + (c31 + 32) * 256 + 16 * (sx ^ (c31 & 15)));
#pragma unroll
        for (int rt = 0; rt < 2; rt++) {
            bf16x8 af = *(const bf16x8*)(woutb + (wv * 64 + rt * 32 + c31) * HID_ + k0);
            yacc[rt][0] = __builtin_amdgcn_mfma_f32_32x32x16_bf16(af, bq0, yacc[rt][0], 0, 0, 0);
            yacc[rt][1] = __builtin_amdgcn_mfma_f32_32x32x16_bf16(af, bq1, yacc[rt][1], 0, 0, 0);
        }
    }

    // ---- bias + RMS over c ----
#pragma unroll
    for (int rt = 0; rt < 2; rt++)
#pragma unroll
        for (int r = 0; r < 16; r++) {
            int rm = (r & 3) + 8 * (r >> 2) + 4 * hf;
            float bo = bl[wv * 64 + rt * 32 + rm];
            yacc[rt][0][r] += bo;
            yacc[rt][1][r] += bo;
        }
#pragma unroll
    for (int ct = 0; ct < 2; ct++) {
        float s = 0.f;
#pragma unroll
        for (int rt = 0; rt < 2; rt++)
#pragma unroll
            for (int r = 0; r < 16; r++) s = fmaf(yacc[rt][ct][r], yacc[rt][ct][r], s);
        s += __shfl_xor(s, 32);
        if (hf == 0) red[wv][ct * 32 + c31] = s;
    }
    __syncthreads();
    if (t < 64) {
        float S = red[0][t] + red[1][t] + red[2][t] + red[3][t];
        nrm[t] = 16.0f / fmaxf(sqrtf(S), 1e-12f);
    }
    __syncthreads();

    float* ob = out + (size_t)b * C_ * N_ + n0;
#pragma unroll
    for (int rt = 0; rt < 2; rt++)
#pragma unroll
        for (int r = 0; r < 16; r++) {
            int rm = (r & 3) + 8 * (r >> 2) + 4 * hf;
            int c  = wv * 64 + rt * 32 + rm;
            float gc = gl[c];
#pragma unroll
            for (int ct = 0; ct < 2; ct++) {
                int n = ct * 32 + c31;
                __builtin_nontemporal_store(yacc[rt][ct][r] * gc * nrm[n],
                                            &ob[(size_t)c * N_ + n]);
            }
        }
}

// ------------------------------------------------------------------
extern "C" void kernel_launch(void* const* d_in, const int* in_sizes, int n_in,
                              void* d_out, int out_size, void* d_ws, size_t ws_size,
                              hipStream_t stream)
{
    const float* x    = (const float*)d_in[0];
    const float* wqkv = (const float*)d_in[1];
    const float* wout = (const float*)d_in[2];
    const float* bout = (const float*)d_in[3];
    const float* g    = (const float*)d_in[4];
    float* out = (float*)d_out;

    short* qtb     = (short*)d_ws;
    short* part16  = qtb + (size_t)B_ * N_ * HID_;
    float* partden = (float*)(part16 + (size_t)2048 * 4 * 1024);
    short* ctxbf   = (short*)(partden + (size_t)2048 * 4 * 32);
    short* wrearr  = ctxbf + (size_t)B_ * H_ * 32 * 32;
    short* woutb   = wrearr + (size_t)12288 * 8;

    k_conv<<<80, 256, 0, stream>>>(wqkv, wout, wrearr, woutb);
    k_qkv<<<1024, 512, 0, stream>>>(x, wrearr, qtb, part16, partden);
    k_red<<<B_ * H_, 256, 0, stream>>>(part16, partden, ctxbf);
    k_out<<<B_ * (N_ / 64), 256, 0, stream>>>(qtb, ctxbf, woutb, bout, g, out);
}